// Round 9
// baseline (188.698 us; speedup 1.0000x reference)
//
#include <hip/hip_runtime.h>
#include <hip/hip_fp16.h>
#include <math.h>

typedef _Float16 half8 __attribute__((ext_vector_type(8)));
typedef float floatx4 __attribute__((ext_vector_type(4)));

#define BB 32
#define SS 48
#define LL 64
#define FF 256
#define NSLICE 2
#define NBLK ((BB * SS) / NSLICE)   // 768 blocks = exactly 3 per CU

// LDS-publish-only barrier: does NOT drain vmcnt (global->VGPR prefetches
// stay in flight). All inter-wave data moves through LDS => lgkmcnt(0) suffices.
#define WAVE_BARRIER() do {                                          \
    asm volatile("s_waitcnt lgkmcnt(0)" ::: "memory");               \
    __builtin_amdgcn_s_barrier();                                    \
    asm volatile("" ::: "memory");                                   \
} while (0)

#define ISSUE_FENCE() asm volatile("" ::: "memory")

// ---- DPP 16-lane reduces on the VALU (not the DS pipe) ----
template <int CTRL>
__device__ __forceinline__ float dpp_add(float x) {
    int y = __builtin_amdgcn_update_dpp(0, __float_as_int(x), CTRL, 0xF, 0xF, true);
    return x + __int_as_float(y);
}
template <int CTRL>
__device__ __forceinline__ float dpp_max(float x) {
    int y = __builtin_amdgcn_update_dpp(0, __float_as_int(x), CTRL, 0xF, 0xF, true);
    return fmaxf(x, __int_as_float(y));
}
__device__ __forceinline__ float row16_sum(float x) {
    x = dpp_add<0xB1>(x);   // quad_perm xor1
    x = dpp_add<0x4E>(x);   // quad_perm xor2
    x = dpp_add<0x124>(x);  // row_ror:4
    x = dpp_add<0x128>(x);  // row_ror:8
    return x;
}
__device__ __forceinline__ float row16_max(float x) {
    x = dpp_max<0xB1>(x);
    x = dpp_max<0x4E>(x);
    x = dpp_max<0x124>(x);
    x = dpp_max<0x128>(x);
    return x;
}

// ---- prep: W1 -> fp16 MFMA-B fragment order (hi only) ----
//   flat = ((kt*16 + nt)*64 + lane)*8 + j ; element = W1[kt*32+(lane>>4)*8+j][nt*16+(lane&15)]
__global__ __launch_bounds__(256) void prep_w(const float* __restrict__ W1,
                                              _Float16* __restrict__ whi) {
    int idx = blockIdx.x * 256 + threadIdx.x;
    int j    = idx & 7;
    int lane = (idx >> 3) & 63;
    int nt   = (idx >> 9) & 15;
    int kt   = idx >> 13;
    int k = kt * 32 + ((lane >> 4) & 3) * 8 + j;
    int n = nt * 16 + (lane & 15);
    whi[idx] = (_Float16)W1[k * FF + n];
}

// ---- fused kernel: 3-domain round ----
// Single 32 KiB A-buffer (the araw registers ARE the cross-slice pipeline
// buffer; LDS dbuf was redundant) + BAR_W guarding overwrite. LDS 34.8 KB,
// NSLICE=2, 768 blocks -> 3 independent barrier-domains per CU (was 2).
// NSLICE=2 keeps both slices in the same batch b (48 even), so all softmax
// operands + weight fragments hoist out of the slice loop.
__global__ __launch_bounds__(512, 6) void ida_mfma(
    const float* __restrict__ features,
    const float* __restrict__ src_locs,
    const float* __restrict__ tar_locs,
    const _Float16* __restrict__ whi,
    const float* __restrict__ b1,
    const float* __restrict__ W2,
    const float* __restrict__ b2,
    float* __restrict__ out)
{
    __shared__ _Float16 Ahi[16384];   // 32 KiB: 64x256 fp16 A (single buffer)
    __shared__ float SP[8 * LL];      // layer-2 partials [wave][station] (2 KiB)

    const int t    = threadIdx.x;
    const int w    = t >> 6;          // wave 0..7 -> owns cols 32w..32w+31
    const int lane = t & 63;
    const int quad = lane >> 4;
    const int l16  = lane & 15;
    const int g    = blockIdx.x;
    const int b    = (g * NSLICE) / SS;   // same b for both slices (48 even)

    // ---- hoisted loop-invariant loads ----
    float sx = src_locs[(b * LL + lane) * 2 + 0];
    float sy = src_locs[(b * LL + lane) * 2 + 1];
    float tx = tar_locs[b * 2 + 0];
    float ty = tar_locs[b * 2 + 1];
    float b2v = b2[0];
    float b1v[2], w2v[2];
    #pragma unroll
    for (int ntl = 0; ntl < 2; ++ntl) {
        int n = (w * 2 + ntl) * 16 + l16;
        b1v[ntl] = b1[n];
        w2v[ntl] = W2[n];
    }
    ISSUE_FENCE();

    // ---- prologue: issue A raw loads for slice 0 ----
    float4 araw[8];
    {
        const float* Xg0 = features + (size_t)(g * NSLICE) * (LL * FF);
        #pragma unroll
        for (int it = 0; it < 4; ++it) {
            const float4* p = (const float4*)(Xg0 + (it * 16 + l16) * FF + w * 32 + quad * 8);
            araw[2 * it + 0] = p[0];
            araw[2 * it + 1] = p[1];
        }
    }
    ISSUE_FENCE();

    #pragma unroll
    for (int i = 0; i < NSLICE; ++i) {
        const int bs = g * NSLICE + i;

        // ---- stage A from araw (waits araw only) ----
        // element (row r, col c) at Ahi[(G*64 + lane)*8 + j]:
        //   row = (G>>3)*16 + l16, col = (G&7)*32 + quad*8 + j
        #pragma unroll
        for (int it = 0; it < 4; ++it) {
            int G = it * 8 + w;
            float4 x0 = araw[2 * it + 0], x1 = araw[2 * it + 1];
            float xs[8] = {x0.x, x0.y, x0.z, x0.w, x1.x, x1.y, x1.z, x1.w};
            half8 hi;
            #pragma unroll
            for (int j = 0; j < 8; ++j) hi[j] = (_Float16)xs[j];
            *((half8*)&Ahi[(G * 64 + lane) * 8]) = hi;
        }

        // ---- B chunks 0,1 preload (depth-3 pipeline); in flight across barrier ----
        half8 bq[3][2];
        #pragma unroll
        for (int c = 0; c < 2; ++c)
            #pragma unroll
            for (int ntl = 0; ntl < 2; ++ntl)
                bq[c][ntl] = *((const half8*)(whi + ((size_t)(c * 16 + (w * 2 + ntl)) * 64 + lane) * 8));
        ISSUE_FENCE();

        WAVE_BARRIER();   // BAR_A: A(i) published; B chunks still in flight

        floatx4 acc[4][2] = {};   // [mt][ntl] -> 32 AGPRs

        // ---- GEMM: 8 kt steps, depth-3 B pipeline, 1 MFMA per (kt,mt,ntl) ----
        #pragma unroll
        for (int kt = 0; kt < 8; ++kt) {
            if (kt < 6) {
                #pragma unroll
                for (int ntl = 0; ntl < 2; ++ntl)
                    bq[(kt + 2) % 3][ntl] = *((const half8*)(whi + ((size_t)((kt + 2) * 16 + (w * 2 + ntl)) * 64 + lane) * 8));
            }
            #pragma unroll
            for (int mt = 0; mt < 4; ++mt) {
                half8 ahi = *((half8*)&Ahi[((mt * 8 + kt) * 64 + lane) * 8]);
                #pragma unroll
                for (int ntl = 0; ntl < 2; ++ntl)
                    acc[mt][ntl] = __builtin_amdgcn_mfma_f32_16x16x32_f16(ahi, bq[kt % 3][ntl], acc[mt][ntl], 0, 0, 0);
            }
        }

        // ---- issue NEXT slice's A loads now (bq dead -> no reg-pressure spike;
        //      after all B loads -> no cascade drain); they complete under
        //      fold+softmax+wsum and land in LDS only after BAR_W ----
        if (i + 1 < NSLICE) {
            const float* Xgn = features + (size_t)(bs + 1) * (LL * FF);
            #pragma unroll
            for (int it = 0; it < 4; ++it) {
                const float4* p = (const float4*)(Xgn + (it * 16 + l16) * FF + w * 32 + quad * 8);
                araw[2 * it + 0] = p[0];
                araw[2 * it + 1] = p[1];
            }
            ISSUE_FENCE();
        }

        // ---- layer-2 fold: DPP row-reduce (VALU) ----
        #pragma unroll
        for (int mt = 0; mt < 4; ++mt) {
            #pragma unroll
            for (int r = 0; r < 4; ++r) {
                float p = 0.f;
                #pragma unroll
                for (int ntl = 0; ntl < 2; ++ntl) {
                    float h = fmaxf(acc[mt][ntl][r] + b1v[ntl], 0.f);
                    p = fmaf(h, w2v[ntl], p);
                }
                p = row16_sum(p);
                if (l16 == 0) SP[w * LL + mt * 16 + quad * 4 + r] = p;
            }
        }

        WAVE_BARRIER();   // BAR_SP: SP published

        // ---- redundant per-wave softmax (station = lane) ----
        float s = SP[0 * LL + lane] + SP[1 * LL + lane] + SP[2 * LL + lane] + SP[3 * LL + lane]
                + SP[4 * LL + lane] + SP[5 * LL + lane] + SP[6 * LL + lane] + SP[7 * LL + lane] + b2v;
        float score = fmaxf(s, 0.f);
        float dxv = sx - tx, dyv = sy - ty;
        float inv_d = 1.0f / sqrtf(dxv * dxv + dyv * dyv);
        float logit = score * inv_d;
        float m = row16_max(logit);
        m = fmaxf(m, __shfl_xor(m, 16));
        m = fmaxf(m, __shfl_xor(m, 32));
        float e = __expf(logit - m);
        float se = row16_sum(e);
        se += __shfl_xor(se, 16);
        se += __shfl_xor(se, 32);
        float wgt = e / se;   // weight of station `lane`, valid in all lanes

        // ---- weighted sum: Ahi read along staging pattern (conflict-free) +
        //      DPP row-reduce over l16; lane l16==0 stores 8 cols direct ----
        float o8[8] = {0.f, 0.f, 0.f, 0.f, 0.f, 0.f, 0.f, 0.f};
        #pragma unroll
        for (int it = 0; it < 4; ++it) {
            float wr = __shfl(wgt, it * 16 + l16);
            half8 hv = *((half8*)&Ahi[((it * 8 + w) * 64 + lane) * 8]);
            #pragma unroll
            for (int j = 0; j < 8; ++j)
                o8[j] = fmaf((float)hv[j], wr, o8[j]);
        }
        #pragma unroll
        for (int j = 0; j < 8; ++j)
            o8[j] = row16_sum(o8[j]);
        if (l16 == 0) {
            float* op = out + (size_t)bs * FF + w * 32 + quad * 8;
            float4 s0 = {o8[0], o8[1], o8[2], o8[3]};
            float4 s1 = {o8[4], o8[5], o8[6], o8[7]};
            *((float4*)op) = s0;
            *((float4*)(op + 4)) = s1;
        }

        if (i + 1 < NSLICE)
            WAVE_BARRIER();   // BAR_W: all wsum LDS reads done before restage
    }
}

extern "C" void kernel_launch(void* const* d_in, const int* in_sizes, int n_in,
                              void* d_out, int out_size, void* d_ws, size_t ws_size,
                              hipStream_t stream) {
    const float* features = (const float*)d_in[0];
    const float* src_locs = (const float*)d_in[1];
    const float* tar_locs = (const float*)d_in[2];
    const float* W1       = (const float*)d_in[3];
    const float* b1       = (const float*)d_in[4];
    const float* W2       = (const float*)d_in[5];
    const float* b2       = (const float*)d_in[6];
    float* out = (float*)d_out;

    _Float16* whi = (_Float16*)d_ws;               // 128 KiB

    prep_w<<<dim3(FF * FF / 256), dim3(256), 0, stream>>>(W1, whi);
    ida_mfma<<<dim3(NBLK), dim3(512), 0, stream>>>(
        features, src_locs, tar_locs, whi, b1, W2, b2, out);
}

// Round 10
// 183.630 us; speedup vs baseline: 1.0276x; 1.0276x over previous
//
#include <hip/hip_runtime.h>
#include <hip/hip_fp16.h>
#include <math.h>

typedef _Float16 half8 __attribute__((ext_vector_type(8)));
typedef float floatx4 __attribute__((ext_vector_type(4)));

#define BB 32
#define SS 48
#define LL 64
#define FF 256
#define NSLICE 3
#define NBLK ((BB * SS) / NSLICE)   // 512 blocks = exactly 2 per CU (reg ceiling)

// LDS-publish-only barrier: does NOT drain vmcnt (global->VGPR prefetches
// stay in flight). All inter-wave data moves through LDS => lgkmcnt(0) suffices.
#define WAVE_BARRIER() do {                                          \
    asm volatile("s_waitcnt lgkmcnt(0)" ::: "memory");               \
    __builtin_amdgcn_s_barrier();                                    \
    asm volatile("" ::: "memory");                                   \
} while (0)

#define ISSUE_FENCE() asm volatile("" ::: "memory")

// ---- DPP 16-lane reduces on the VALU (not the DS pipe) ----
template <int CTRL>
__device__ __forceinline__ float dpp_add(float x) {
    int y = __builtin_amdgcn_update_dpp(0, __float_as_int(x), CTRL, 0xF, 0xF, true);
    return x + __int_as_float(y);
}
template <int CTRL>
__device__ __forceinline__ float dpp_max(float x) {
    int y = __builtin_amdgcn_update_dpp(0, __float_as_int(x), CTRL, 0xF, 0xF, true);
    return fmaxf(x, __int_as_float(y));
}
__device__ __forceinline__ float row16_sum(float x) {
    x = dpp_add<0xB1>(x);   // quad_perm xor1
    x = dpp_add<0x4E>(x);   // quad_perm xor2
    x = dpp_add<0x124>(x);  // row_ror:4
    x = dpp_add<0x128>(x);  // row_ror:8
    return x;
}
__device__ __forceinline__ float row16_max(float x) {
    x = dpp_max<0xB1>(x);
    x = dpp_max<0x4E>(x);
    x = dpp_max<0x124>(x);
    x = dpp_max<0x128>(x);
    return x;
}

// ---- prep: W1 -> fp16 MFMA-B fragment order (hi only) ----
//   flat = ((kt*16 + nt)*64 + lane)*8 + j ; element = W1[kt*32+(lane>>4)*8+j][nt*16+(lane&15)]
__global__ __launch_bounds__(256) void prep_w(const float* __restrict__ W1,
                                              _Float16* __restrict__ whi) {
    int idx = blockIdx.x * 256 + threadIdx.x;
    int j    = idx & 7;
    int lane = (idx >> 3) & 63;
    int nt   = (idx >> 9) & 15;
    int kt   = idx >> 13;
    int k = kt * 32 + ((lane >> 4) & 3) * 8 + j;
    int n = nt * 16 + (lane & 15);
    whi[idx] = (_Float16)W1[k * FF + n];
}

// ---- fused kernel: R8 frame + reg-resident wsum ----
// 512 blocks x 3 slices, (512,4) = 2 blocks/CU (the HW reg-granularity
// ceiling for 512-thr blocks; R9 proved 3 domains needs <=64 regs -> spill).
// Ping-pong araw reg sets (arA/arB): wsum(i) reads its own fp32 araw values
// (exactly the elements this thread staged) -> zero DS in the tail, exact
// fp32 weighted sum; prefetch(i+1) fills the other set under fold+softmax.
// Single 32 KiB Ahi buffer (BAR_SP already orders stage(i+1) vs GEMM(i)).
// Misc/weight loads hoisted (slices 3g..3g+2 share batch b since 3|48).
__global__ __launch_bounds__(512, 4) void ida_mfma(
    const float* __restrict__ features,
    const float* __restrict__ src_locs,
    const float* __restrict__ tar_locs,
    const _Float16* __restrict__ whi,
    const float* __restrict__ b1,
    const float* __restrict__ W2,
    const float* __restrict__ b2,
    float* __restrict__ out)
{
    __shared__ _Float16 Ahi[16384];   // 32 KiB: 64x256 fp16 A (single buffer)
    __shared__ float SP[8 * LL];      // layer-2 partials [wave][station] (2 KiB)

    const int t    = threadIdx.x;
    const int w    = t >> 6;          // wave 0..7 -> owns cols 32w..32w+31
    const int lane = t & 63;
    const int quad = lane >> 4;
    const int l16  = lane & 15;
    const int g    = blockIdx.x;
    const int b    = (g * NSLICE) / SS;   // same b for all 3 slices

    // ---- hoisted loop-invariant loads ----
    float sx = src_locs[(b * LL + lane) * 2 + 0];
    float sy = src_locs[(b * LL + lane) * 2 + 1];
    float tx = tar_locs[b * 2 + 0];
    float ty = tar_locs[b * 2 + 1];
    float b2v = b2[0];
    float b1v[2], w2v[2];
    #pragma unroll
    for (int ntl = 0; ntl < 2; ++ntl) {
        int n = (w * 2 + ntl) * 16 + l16;
        b1v[ntl] = b1[n];
        w2v[ntl] = W2[n];
    }
    ISSUE_FENCE();

    float4 arA[8], arB[8];

    // ---- prologue: slice-0 A loads into set A ----
    {
        const float* Xg0 = features + (size_t)(g * NSLICE) * (LL * FF);
        #pragma unroll
        for (int it = 0; it < 4; ++it) {
            const float4* p = (const float4*)(Xg0 + (it * 16 + l16) * FF + w * 32 + quad * 8);
            arA[2 * it + 0] = p[0];
            arA[2 * it + 1] = p[1];
        }
    }
    ISSUE_FENCE();

    // ---- slice body: CUR = this slice's fp32 regs; NXT = prefetch target ----
#define SLICE_BODY(i, CUR, NXT)                                                   \
    {                                                                             \
        const int bs = g * NSLICE + (i);                                          \
        /* stage A from CUR (element (r,c): r=(G>>3)*16+l16, c=(G&7)*32+quad*8+j) */ \
        _Pragma("unroll")                                                         \
        for (int it = 0; it < 4; ++it) {                                          \
            int G = it * 8 + w;                                                   \
            float4 x0 = CUR[2 * it + 0], x1 = CUR[2 * it + 1];                    \
            float xs[8] = {x0.x, x0.y, x0.z, x0.w, x1.x, x1.y, x1.z, x1.w};       \
            half8 hi;                                                             \
            _Pragma("unroll")                                                     \
            for (int j = 0; j < 8; ++j) hi[j] = (_Float16)xs[j];                  \
            *((half8*)&Ahi[(G * 64 + lane) * 8]) = hi;                            \
        }                                                                         \
        /* B chunks 0,1 preload (depth-3); in flight across barrier */            \
        half8 bq[3][2];                                                           \
        _Pragma("unroll")                                                         \
        for (int c = 0; c < 2; ++c)                                               \
            _Pragma("unroll")                                                     \
            for (int ntl = 0; ntl < 2; ++ntl)                                     \
                bq[c][ntl] = *((const half8*)(whi +                               \
                    ((size_t)(c * 16 + (w * 2 + ntl)) * 64 + lane) * 8));         \
        ISSUE_FENCE();                                                            \
        WAVE_BARRIER();   /* BAR_A: A published; B chunks in flight */            \
        floatx4 acc[4][2] = {};                                                   \
        _Pragma("unroll")                                                         \
        for (int kt = 0; kt < 8; ++kt) {                                          \
            if (kt < 6) {                                                         \
                _Pragma("unroll")                                                 \
                for (int ntl = 0; ntl < 2; ++ntl)                                 \
                    bq[(kt + 2) % 3][ntl] = *((const half8*)(whi +                \
                        ((size_t)((kt + 2) * 16 + (w * 2 + ntl)) * 64 + lane) * 8)); \
            }                                                                     \
            _Pragma("unroll")                                                     \
            for (int mt = 0; mt < 4; ++mt) {                                      \
                half8 ahi = *((half8*)&Ahi[((mt * 8 + kt) * 64 + lane) * 8]);     \
                _Pragma("unroll")                                                 \
                for (int ntl = 0; ntl < 2; ++ntl)                                 \
                    acc[mt][ntl] = __builtin_amdgcn_mfma_f32_16x16x32_f16(        \
                        ahi, bq[kt % 3][ntl], acc[mt][ntl], 0, 0, 0);             \
            }                                                                     \
        }                                                                         \
        /* prefetch next slice into NXT (bq dead; after all B loads) */           \
        if ((i) + 1 < NSLICE) {                                                   \
            const float* Xgn = features + (size_t)(bs + 1) * (LL * FF);           \
            _Pragma("unroll")                                                     \
            for (int it = 0; it < 4; ++it) {                                      \
                const float4* p = (const float4*)(Xgn + (it * 16 + l16) * FF      \
                                                  + w * 32 + quad * 8);           \
                NXT[2 * it + 0] = p[0];                                           \
                NXT[2 * it + 1] = p[1];                                           \
            }                                                                     \
            ISSUE_FENCE();                                                        \
        }                                                                         \
        /* layer-2 fold: DPP row-reduce (VALU) */                                 \
        _Pragma("unroll")                                                         \
        for (int mt = 0; mt < 4; ++mt) {                                          \
            _Pragma("unroll")                                                     \
            for (int r = 0; r < 4; ++r) {                                         \
                float p = 0.f;                                                    \
                _Pragma("unroll")                                                 \
                for (int ntl = 0; ntl < 2; ++ntl) {                               \
                    float h = fmaxf(acc[mt][ntl][r] + b1v[ntl], 0.f);             \
                    p = fmaf(h, w2v[ntl], p);                                     \
                }                                                                 \
                p = row16_sum(p);                                                 \
                if (l16 == 0) SP[w * LL + mt * 16 + quad * 4 + r] = p;            \
            }                                                                     \
        }                                                                         \
        WAVE_BARRIER();   /* BAR_SP: SP published (also orders next stage) */     \
        /* redundant per-wave softmax (station = lane) */                         \
        float s = SP[0 * LL + lane] + SP[1 * LL + lane] + SP[2 * LL + lane]       \
                + SP[3 * LL + lane] + SP[4 * LL + lane] + SP[5 * LL + lane]       \
                + SP[6 * LL + lane] + SP[7 * LL + lane] + b2v;                    \
        float score = fmaxf(s, 0.f);                                              \
        float dxv = sx - tx, dyv = sy - ty;                                       \
        float inv_d = 1.0f / sqrtf(dxv * dxv + dyv * dyv);                        \
        float logit = score * inv_d;                                              \
        float m = row16_max(logit);                                               \
        m = fmaxf(m, __shfl_xor(m, 16));                                          \
        m = fmaxf(m, __shfl_xor(m, 32));                                          \
        float e = __expf(logit - m);                                              \
        float se = row16_sum(e);                                                  \
        se += __shfl_xor(se, 16);                                                 \
        se += __shfl_xor(se, 32);                                                 \
        float wgt = e / se;                                                       \
        /* weighted sum from CUR fp32 regs (this thread's own staged elems) */    \
        float o8[8] = {0.f, 0.f, 0.f, 0.f, 0.f, 0.f, 0.f, 0.f};                   \
        _Pragma("unroll")                                                         \
        for (int it = 0; it < 4; ++it) {                                          \
            float wr = __shfl(wgt, it * 16 + l16);                                \
            float4 x0 = CUR[2 * it + 0], x1 = CUR[2 * it + 1];                    \
            o8[0] = fmaf(x0.x, wr, o8[0]);                                        \
            o8[1] = fmaf(x0.y, wr, o8[1]);                                        \
            o8[2] = fmaf(x0.z, wr, o8[2]);                                        \
            o8[3] = fmaf(x0.w, wr, o8[3]);                                        \
            o8[4] = fmaf(x1.x, wr, o8[4]);                                        \
            o8[5] = fmaf(x1.y, wr, o8[5]);                                        \
            o8[6] = fmaf(x1.z, wr, o8[6]);                                        \
            o8[7] = fmaf(x1.w, wr, o8[7]);                                        \
        }                                                                         \
        _Pragma("unroll")                                                         \
        for (int j = 0; j < 8; ++j)                                               \
            o8[j] = row16_sum(o8[j]);                                             \
        if (l16 == 0) {                                                           \
            float* op = out + (size_t)bs * FF + w * 32 + quad * 8;                \
            float4 s0 = {o8[0], o8[1], o8[2], o8[3]};                             \
            float4 s1 = {o8[4], o8[5], o8[6], o8[7]};                             \
            *((float4*)op) = s0;                                                  \
            *((float4*)(op + 4)) = s1;                                            \
        }                                                                         \
    }

    SLICE_BODY(0, arA, arB)
    SLICE_BODY(1, arB, arA)
    SLICE_BODY(2, arA, arB)
#undef SLICE_BODY
}

extern "C" void kernel_launch(void* const* d_in, const int* in_sizes, int n_in,
                              void* d_out, int out_size, void* d_ws, size_t ws_size,
                              hipStream_t stream) {
    const float* features = (const float*)d_in[0];
    const float* src_locs = (const float*)d_in[1];
    const float* tar_locs = (const float*)d_in[2];
    const float* W1       = (const float*)d_in[3];
    const float* b1       = (const float*)d_in[4];
    const float* W2       = (const float*)d_in[5];
    const float* b2       = (const float*)d_in[6];
    float* out = (float*)d_out;

    _Float16* whi = (_Float16*)d_ws;               // 128 KiB

    prep_w<<<dim3(FF * FF / 256), dim3(256), 0, stream>>>(W1, whi);
    ida_mfma<<<dim3(NBLK), dim3(512), 0, stream>>>(
        features, src_locs, tar_locs, whi, b1, W2, b2, out);
}

// Round 11
// 175.854 us; speedup vs baseline: 1.0730x; 1.0442x over previous
//
#include <hip/hip_runtime.h>
#include <hip/hip_fp16.h>
#include <math.h>

typedef _Float16 half8 __attribute__((ext_vector_type(8)));
typedef float floatx4 __attribute__((ext_vector_type(4)));

#define BB 32
#define SS 48
#define LL 64
#define FF 256
#define NSLICE 3
#define NBLK ((BB * SS) / NSLICE)   // 512 blocks, exactly 2 per CU

// LDS-publish-only barrier: does NOT drain vmcnt (global->VGPR prefetches
// stay in flight). All inter-wave data moves through LDS => lgkmcnt(0) suffices.
#define WAVE_BARRIER() do {                                          \
    asm volatile("s_waitcnt lgkmcnt(0)" ::: "memory");               \
    __builtin_amdgcn_s_barrier();                                    \
    asm volatile("" ::: "memory");                                   \
} while (0)

#define ISSUE_FENCE() asm volatile("" ::: "memory")

// ---- DPP 16-lane reduces on the VALU (not the DS pipe) ----
template <int CTRL>
__device__ __forceinline__ float dpp_add(float x) {
    int y = __builtin_amdgcn_update_dpp(0, __float_as_int(x), CTRL, 0xF, 0xF, true);
    return x + __int_as_float(y);
}
template <int CTRL>
__device__ __forceinline__ float dpp_max(float x) {
    int y = __builtin_amdgcn_update_dpp(0, __float_as_int(x), CTRL, 0xF, 0xF, true);
    return fmaxf(x, __int_as_float(y));
}
__device__ __forceinline__ float row16_sum(float x) {
    x = dpp_add<0xB1>(x);   // quad_perm xor1
    x = dpp_add<0x4E>(x);   // quad_perm xor2
    x = dpp_add<0x124>(x);  // row_ror:4
    x = dpp_add<0x128>(x);  // row_ror:8
    return x;
}
__device__ __forceinline__ float row16_max(float x) {
    x = dpp_max<0xB1>(x);
    x = dpp_max<0x4E>(x);
    x = dpp_max<0x124>(x);
    x = dpp_max<0x128>(x);
    return x;
}

// ---- prep: W1 -> fp16 MFMA-B fragment order (hi only) ----
//   flat = ((kt*16 + nt)*64 + lane)*8 + j ; element = W1[kt*32+(lane>>4)*8+j][nt*16+(lane&15)]
__global__ __launch_bounds__(256) void prep_w(const float* __restrict__ W1,
                                              _Float16* __restrict__ whi) {
    int idx = blockIdx.x * 256 + threadIdx.x;
    int j    = idx & 7;
    int lane = (idx >> 3) & 63;
    int nt   = (idx >> 9) & 15;
    int kt   = idx >> 13;
    int k = kt * 32 + ((lane >> 4) & 3) * 8 + j;
    int n = nt * 16 + (lane & 15);
    whi[idx] = (_Float16)W1[k * FF + n];
}

// ---- fused kernel: R8 structure (the measured fixed point) + misc hoist ----
// 512 blocks x 3 S-slices (2 blocks/CU). Double-buffered A (2x32 KiB).
// Next slice's A-loads issued AFTER the GEMM's last B load (no cascade
// drain) and complete under fold+softmax+wsum. B pipeline depth 3.
// R9/R10 lesson: live-state floor is ~100 unified regs; araw(32)+acc(32)+
// bq(24) leaves no room for a second reg set or >4 waves/EU -> any such
// variant spills (WRITE_SIZE 38-57 MB). Stay at (512,4).
// Misc/src/tar loads hoisted: slices 3g..3g+2 share batch b (3 | 48).
__global__ __launch_bounds__(512, 4) void ida_mfma(
    const float* __restrict__ features,
    const float* __restrict__ src_locs,
    const float* __restrict__ tar_locs,
    const _Float16* __restrict__ whi,
    const float* __restrict__ b1,
    const float* __restrict__ W2,
    const float* __restrict__ b2,
    float* __restrict__ out)
{
    __shared__ _Float16 Ahi[2][16384];   // 64 KiB: double-buffered 64x256 fp16 A
    __shared__ float SP[8 * LL];         // layer-2 partials [wave][station] (2 KiB)

    const int t    = threadIdx.x;
    const int w    = t >> 6;          // wave 0..7 -> owns cols 32w..32w+31
    const int lane = t & 63;
    const int quad = lane >> 4;
    const int l16  = lane & 15;
    const int g    = blockIdx.x;
    const int b    = (g * NSLICE) / SS;   // same b for all 3 slices (3 | 48)

    // ---- hoisted loop-invariant loads ----
    float sx = src_locs[(b * LL + lane) * 2 + 0];
    float sy = src_locs[(b * LL + lane) * 2 + 1];
    float tx = tar_locs[b * 2 + 0];
    float ty = tar_locs[b * 2 + 1];
    float b2v = b2[0];
    float b1v[2], w2v[2];
    #pragma unroll
    for (int ntl = 0; ntl < 2; ++ntl) {
        int n = (w * 2 + ntl) * 16 + l16;
        b1v[ntl] = b1[n];
        w2v[ntl] = W2[n];
    }
    ISSUE_FENCE();

    // ---- prologue: issue A raw loads for slice 0 ----
    float4 araw[8];
    {
        const float* Xg0 = features + (size_t)(g * NSLICE) * (LL * FF);
        #pragma unroll
        for (int it = 0; it < 4; ++it) {
            const float4* p = (const float4*)(Xg0 + (it * 16 + l16) * FF + w * 32 + quad * 8);
            araw[2 * it + 0] = p[0];
            araw[2 * it + 1] = p[1];
        }
    }
    ISSUE_FENCE();

    #pragma unroll
    for (int i = 0; i < NSLICE; ++i) {
        const int bs = g * NSLICE + i;
        _Float16* Abuf = &Ahi[i & 1][0];

        // ---- stage A from araw (waits araw only) ----
        // element (row r, col c) at Abuf[(G*64 + lane)*8 + j]:
        //   row = (G>>3)*16 + l16, col = (G&7)*32 + quad*8 + j
        #pragma unroll
        for (int it = 0; it < 4; ++it) {
            int G = it * 8 + w;
            float4 x0 = araw[2 * it + 0], x1 = araw[2 * it + 1];
            float xs[8] = {x0.x, x0.y, x0.z, x0.w, x1.x, x1.y, x1.z, x1.w};
            half8 hi;
            #pragma unroll
            for (int j = 0; j < 8; ++j) hi[j] = (_Float16)xs[j];
            *((half8*)&Abuf[(G * 64 + lane) * 8]) = hi;
        }

        // ---- B chunks 0,1 preload (depth-3 pipeline); in flight across barrier ----
        half8 bq[3][2];
        #pragma unroll
        for (int c = 0; c < 2; ++c)
            #pragma unroll
            for (int ntl = 0; ntl < 2; ++ntl)
                bq[c][ntl] = *((const half8*)(whi + ((size_t)(c * 16 + (w * 2 + ntl)) * 64 + lane) * 8));
        ISSUE_FENCE();

        WAVE_BARRIER();   // BAR_A: A(i) published; B chunks still in flight

        floatx4 acc[4][2] = {};   // [mt][ntl] -> 32 AGPRs

        // ---- GEMM: 8 kt steps, depth-3 B pipeline, 1 MFMA per (kt,mt,ntl) ----
        #pragma unroll
        for (int kt = 0; kt < 8; ++kt) {
            if (kt < 6) {
                #pragma unroll
                for (int ntl = 0; ntl < 2; ++ntl)
                    bq[(kt + 2) % 3][ntl] = *((const half8*)(whi + ((size_t)((kt + 2) * 16 + (w * 2 + ntl)) * 64 + lane) * 8));
            }
            #pragma unroll
            for (int mt = 0; mt < 4; ++mt) {
                half8 ahi = *((half8*)&Abuf[((mt * 8 + kt) * 64 + lane) * 8]);
                #pragma unroll
                for (int ntl = 0; ntl < 2; ++ntl)
                    acc[mt][ntl] = __builtin_amdgcn_mfma_f32_16x16x32_f16(ahi, bq[kt % 3][ntl], acc[mt][ntl], 0, 0, 0);
            }
        }

        // ---- issue NEXT slice's A loads now (bq dead, after all B loads ->
        //      no cascade drain); they complete under fold+softmax+wsum ----
        if (i + 1 < NSLICE) {
            const float* Xgn = features + (size_t)(bs + 1) * (LL * FF);
            #pragma unroll
            for (int it = 0; it < 4; ++it) {
                const float4* p = (const float4*)(Xgn + (it * 16 + l16) * FF + w * 32 + quad * 8);
                araw[2 * it + 0] = p[0];
                araw[2 * it + 1] = p[1];
            }
            ISSUE_FENCE();
        }

        // ---- layer-2 fold: DPP row-reduce (VALU) ----
        #pragma unroll
        for (int mt = 0; mt < 4; ++mt) {
            #pragma unroll
            for (int r = 0; r < 4; ++r) {
                float p = 0.f;
                #pragma unroll
                for (int ntl = 0; ntl < 2; ++ntl) {
                    float h = fmaxf(acc[mt][ntl][r] + b1v[ntl], 0.f);
                    p = fmaf(h, w2v[ntl], p);
                }
                p = row16_sum(p);
                if (l16 == 0) SP[w * LL + mt * 16 + quad * 4 + r] = p;
            }
        }

        WAVE_BARRIER();   // BAR_SP: SP published

        // ---- redundant per-wave softmax (station = lane) ----
        float s = SP[0 * LL + lane] + SP[1 * LL + lane] + SP[2 * LL + lane] + SP[3 * LL + lane]
                + SP[4 * LL + lane] + SP[5 * LL + lane] + SP[6 * LL + lane] + SP[7 * LL + lane] + b2v;
        float score = fmaxf(s, 0.f);
        float dxv = sx - tx, dyv = sy - ty;
        float inv_d = 1.0f / sqrtf(dxv * dxv + dyv * dyv);
        float logit = score * inv_d;
        float m = row16_max(logit);
        m = fmaxf(m, __shfl_xor(m, 16));
        m = fmaxf(m, __shfl_xor(m, 32));
        float e = __expf(logit - m);
        float se = row16_sum(e);
        se += __shfl_xor(se, 16);
        se += __shfl_xor(se, 32);
        float wgt = e / se;   // weight of station `lane`, valid in all lanes

        // ---- weighted sum: Abuf read along staging pattern (conflict-free) +
        //      DPP row-reduce over l16; lane l16==0 stores 8 cols direct ----
        float o8[8] = {0.f, 0.f, 0.f, 0.f, 0.f, 0.f, 0.f, 0.f};
        #pragma unroll
        for (int it = 0; it < 4; ++it) {
            float wr = __shfl(wgt, it * 16 + l16);
            half8 hv = *((half8*)&Abuf[((it * 8 + w) * 64 + lane) * 8]);
            #pragma unroll
            for (int j = 0; j < 8; ++j)
                o8[j] = fmaf((float)hv[j], wr, o8[j]);
        }
        #pragma unroll
        for (int j = 0; j < 8; ++j)
            o8[j] = row16_sum(o8[j]);
        if (l16 == 0) {
            float* op = out + (size_t)bs * FF + w * 32 + quad * 8;
            float4 s0 = {o8[0], o8[1], o8[2], o8[3]};
            float4 s1 = {o8[4], o8[5], o8[6], o8[7]};
            *((float4*)op) = s0;
            *((float4*)(op + 4)) = s1;
        }
        // next iteration's stage writes the OTHER A buffer; BAR_A(i+1) orders
        // it against this slice's reads. SP rewrite is fenced by BAR_A(i+1).
    }
}

extern "C" void kernel_launch(void* const* d_in, const int* in_sizes, int n_in,
                              void* d_out, int out_size, void* d_ws, size_t ws_size,
                              hipStream_t stream) {
    const float* features = (const float*)d_in[0];
    const float* src_locs = (const float*)d_in[1];
    const float* tar_locs = (const float*)d_in[2];
    const float* W1       = (const float*)d_in[3];
    const float* b1       = (const float*)d_in[4];
    const float* W2       = (const float*)d_in[5];
    const float* b2       = (const float*)d_in[6];
    float* out = (float*)d_out;

    _Float16* whi = (_Float16*)d_ws;               // 128 KiB

    prep_w<<<dim3(FF * FF / 256), dim3(256), 0, stream>>>(W1, whi);
    ida_mfma<<<dim3(NBLK), dim3(512), 0, stream>>>(
        features, src_locs, tar_locs, whi, b1, W2, b2, out);
}

// Round 12
// 166.584 us; speedup vs baseline: 1.1327x; 1.0556x over previous
//
#include <hip/hip_runtime.h>
#include <hip/hip_fp16.h>
#include <math.h>

typedef _Float16 half8 __attribute__((ext_vector_type(8)));
typedef float floatx4 __attribute__((ext_vector_type(4)));

#define BB 32
#define SS 48
#define LL 64
#define FF 256
#define NSLICE 3
#define NBLK ((BB * SS) / NSLICE)   // 512 blocks, exactly 2 per CU

// LDS-publish-only barrier: does NOT drain vmcnt (global->VGPR prefetches
// stay in flight). All inter-wave data moves through LDS => lgkmcnt(0) suffices.
#define WAVE_BARRIER() do {                                          \
    asm volatile("s_waitcnt lgkmcnt(0)" ::: "memory");               \
    __builtin_amdgcn_s_barrier();                                    \
    asm volatile("" ::: "memory");                                   \
} while (0)

#define ISSUE_FENCE() asm volatile("" ::: "memory")

// ---- DPP 16-lane reduces on the VALU (not the DS pipe) ----
template <int CTRL>
__device__ __forceinline__ float dpp_add(float x) {
    int y = __builtin_amdgcn_update_dpp(0, __float_as_int(x), CTRL, 0xF, 0xF, true);
    return x + __int_as_float(y);
}
template <int CTRL>
__device__ __forceinline__ float dpp_max(float x) {
    int y = __builtin_amdgcn_update_dpp(0, __float_as_int(x), CTRL, 0xF, 0xF, true);
    return fmaxf(x, __int_as_float(y));
}
__device__ __forceinline__ float row16_sum(float x) {
    x = dpp_add<0xB1>(x);   // quad_perm xor1
    x = dpp_add<0x4E>(x);   // quad_perm xor2
    x = dpp_add<0x124>(x);  // row_ror:4
    x = dpp_add<0x128>(x);  // row_ror:8
    return x;
}
__device__ __forceinline__ float row16_max(float x) {
    x = dpp_max<0xB1>(x);
    x = dpp_max<0x4E>(x);
    x = dpp_max<0x124>(x);
    x = dpp_max<0x128>(x);
    return x;
}

// ---- prep: W1 -> fp16 MFMA-B fragment order (hi only) ----
//   flat = ((kt*16 + nt)*64 + lane)*8 + j ; element = W1[kt*32+(lane>>4)*8+j][nt*16+(lane&15)]
__global__ __launch_bounds__(256) void prep_w(const float* __restrict__ W1,
                                              _Float16* __restrict__ whi) {
    int idx = blockIdx.x * 256 + threadIdx.x;
    int j    = idx & 7;
    int lane = (idx >> 3) & 63;
    int nt   = (idx >> 9) & 15;
    int kt   = idx >> 13;
    int k = kt * 32 + ((lane >> 4) & 3) * 8 + j;
    int n = nt * 16 + (lane & 15);
    whi[idx] = (_Float16)W1[k * FF + n];
}

// ---- fused kernel: R8 (the measured best) + kt-alternating B reuse ----
// 512 blocks x 3 S-slices (2 blocks/CU). Double-buffered A (2x32 KiB).
// Next slice's A-loads issued AFTER the GEMM's last B load (no cascade
// drain) and complete under fold+softmax+wsum.
// NEW: B (whi) is slice-invariant; slices run fwd/bwd/fwd over kt so the
// depth-3 bq rotation's end state {6,7} / {0,1,2} is exactly the next
// slice's entry state -> per-slice B0/B1 preload deleted for slices 1,2
// (two L2 round-trips off the BAR_A->GEMM critical path, zero reg cost).
// R9/R10 lesson: live-state floor ~100 unified regs; stay at (512,4).
__global__ __launch_bounds__(512, 4) void ida_mfma(
    const float* __restrict__ features,
    const float* __restrict__ src_locs,
    const float* __restrict__ tar_locs,
    const _Float16* __restrict__ whi,
    const float* __restrict__ b1,
    const float* __restrict__ W2,
    const float* __restrict__ b2,
    float* __restrict__ out)
{
    __shared__ _Float16 Ahi[2][16384];   // 64 KiB: double-buffered 64x256 fp16 A
    __shared__ float SP[8 * LL];         // layer-2 partials [wave][station] (2 KiB)

    const int t    = threadIdx.x;
    const int w    = t >> 6;          // wave 0..7 -> owns cols 32w..32w+31
    const int lane = t & 63;
    const int quad = lane >> 4;
    const int l16  = lane & 15;
    const int g    = blockIdx.x;

    // ---- loop-invariant weight fragments ----
    float b1v[2], w2v[2];
    #pragma unroll
    for (int ntl = 0; ntl < 2; ++ntl) {
        int n = (w * 2 + ntl) * 16 + l16;
        b1v[ntl] = b1[n];
        w2v[ntl] = W2[n];
    }
    ISSUE_FENCE();

    // ---- prologue: issue A raw loads for slice 0 ----
    float4 araw[8];
    {
        const float* Xg0 = features + (size_t)(g * NSLICE) * (LL * FF);
        #pragma unroll
        for (int it = 0; it < 4; ++it) {
            const float4* p = (const float4*)(Xg0 + (it * 16 + l16) * FF + w * 32 + quad * 8);
            araw[2 * it + 0] = p[0];
            araw[2 * it + 1] = p[1];
        }
    }
    ISSUE_FENCE();

    half8 bq[3][2];   // depth-3 B rotation; persists ACROSS slices

    #pragma unroll
    for (int i = 0; i < NSLICE; ++i) {
        const int bs = g * NSLICE + i;
        const int b  = bs / SS;
        _Float16* Abuf = &Ahi[i & 1][0];

        // ---- per-slice misc loads (tiny, L2-hot; consumed at softmax) ----
        float sx = src_locs[(b * LL + lane) * 2 + 0];
        float sy = src_locs[(b * LL + lane) * 2 + 1];
        float tx = tar_locs[b * 2 + 0];
        float ty = tar_locs[b * 2 + 1];
        float b2v = b2[0];
        ISSUE_FENCE();

        // ---- stage A from araw (waits araw only) ----
        // element (row r, col c) at Abuf[(G*64 + lane)*8 + j]:
        //   row = (G>>3)*16 + l16, col = (G&7)*32 + quad*8 + j
        #pragma unroll
        for (int it = 0; it < 4; ++it) {
            int G = it * 8 + w;
            float4 x0 = araw[2 * it + 0], x1 = araw[2 * it + 1];
            float xs[8] = {x0.x, x0.y, x0.z, x0.w, x1.x, x1.y, x1.z, x1.w};
            half8 hi;
            #pragma unroll
            for (int j = 0; j < 8; ++j) hi[j] = (_Float16)xs[j];
            *((half8*)&Abuf[(G * 64 + lane) * 8]) = hi;
        }

        // ---- B chunks 0,1 preload: SLICE 0 ONLY (later slices inherit the
        //      rotation's end state: fwd ends {6,7}, bwd ends {0,1,2}) ----
        if (i == 0) {
            #pragma unroll
            for (int c = 0; c < 2; ++c)
                #pragma unroll
                for (int ntl = 0; ntl < 2; ++ntl)
                    bq[c][ntl] = *((const half8*)(whi + ((size_t)(c * 16 + (w * 2 + ntl)) * 64 + lane) * 8));
            ISSUE_FENCE();
        }

        WAVE_BARRIER();   // BAR_A: A(i) published; B chunks (slice 0) still in flight

        floatx4 acc[4][2] = {};   // [mt][ntl] -> 32 AGPRs

        // ---- GEMM: 8 kt steps, depth-3 B rotation; fwd for even i, bwd for odd ----
        if ((i & 1) == 0) {
            // forward: entry needs chunks 0,1 in slots 0,1; exit leaves 6,7
            #pragma unroll
            for (int kt = 0; kt < 8; ++kt) {
                if (kt < 6) {
                    #pragma unroll
                    for (int ntl = 0; ntl < 2; ++ntl)
                        bq[(kt + 2) % 3][ntl] = *((const half8*)(whi + ((size_t)((kt + 2) * 16 + (w * 2 + ntl)) * 64 + lane) * 8));
                }
                #pragma unroll
                for (int mt = 0; mt < 4; ++mt) {
                    half8 ahi = *((half8*)&Abuf[((mt * 8 + kt) * 64 + lane) * 8]);
                    #pragma unroll
                    for (int ntl = 0; ntl < 2; ++ntl)
                        acc[mt][ntl] = __builtin_amdgcn_mfma_f32_16x16x32_f16(ahi, bq[kt % 3][ntl], acc[mt][ntl], 0, 0, 0);
                }
            }
        } else {
            // backward: entry needs chunks 7,6 in slots 1,0 (fwd exit state);
            // exit leaves 0,1,2 in slots 0,1,2 (next fwd entry state)
            #pragma unroll
            for (int kt = 7; kt >= 0; --kt) {
                if (kt >= 2) {
                    #pragma unroll
                    for (int ntl = 0; ntl < 2; ++ntl)
                        bq[(kt - 2) % 3][ntl] = *((const half8*)(whi + ((size_t)((kt - 2) * 16 + (w * 2 + ntl)) * 64 + lane) * 8));
                }
                #pragma unroll
                for (int mt = 0; mt < 4; ++mt) {
                    half8 ahi = *((half8*)&Abuf[((mt * 8 + kt) * 64 + lane) * 8]);
                    #pragma unroll
                    for (int ntl = 0; ntl < 2; ++ntl)
                        acc[mt][ntl] = __builtin_amdgcn_mfma_f32_16x16x32_f16(ahi, bq[kt % 3][ntl], acc[mt][ntl], 0, 0, 0);
                }
            }
        }

        // ---- issue NEXT slice's A loads now (after all B loads -> no cascade
        //      drain); they complete under fold+softmax+wsum ----
        if (i + 1 < NSLICE) {
            const float* Xgn = features + (size_t)(bs + 1) * (LL * FF);
            #pragma unroll
            for (int it = 0; it < 4; ++it) {
                const float4* p = (const float4*)(Xgn + (it * 16 + l16) * FF + w * 32 + quad * 8);
                araw[2 * it + 0] = p[0];
                araw[2 * it + 1] = p[1];
            }
            ISSUE_FENCE();
        }

        // ---- layer-2 fold: DPP row-reduce (VALU) ----
        #pragma unroll
        for (int mt = 0; mt < 4; ++mt) {
            #pragma unroll
            for (int r = 0; r < 4; ++r) {
                float p = 0.f;
                #pragma unroll
                for (int ntl = 0; ntl < 2; ++ntl) {
                    float h = fmaxf(acc[mt][ntl][r] + b1v[ntl], 0.f);
                    p = fmaf(h, w2v[ntl], p);
                }
                p = row16_sum(p);
                if (l16 == 0) SP[w * LL + mt * 16 + quad * 4 + r] = p;
            }
        }

        WAVE_BARRIER();   // BAR_SP: SP published

        // ---- redundant per-wave softmax (station = lane) ----
        float s = SP[0 * LL + lane] + SP[1 * LL + lane] + SP[2 * LL + lane] + SP[3 * LL + lane]
                + SP[4 * LL + lane] + SP[5 * LL + lane] + SP[6 * LL + lane] + SP[7 * LL + lane] + b2v;
        float score = fmaxf(s, 0.f);
        float dxv = sx - tx, dyv = sy - ty;
        float inv_d = 1.0f / sqrtf(dxv * dxv + dyv * dyv);
        float logit = score * inv_d;
        float m = row16_max(logit);
        m = fmaxf(m, __shfl_xor(m, 16));
        m = fmaxf(m, __shfl_xor(m, 32));
        float e = __expf(logit - m);
        float se = row16_sum(e);
        se += __shfl_xor(se, 16);
        se += __shfl_xor(se, 32);
        float wgt = e / se;   // weight of station `lane`, valid in all lanes

        // ---- weighted sum: Abuf read along staging pattern (conflict-free) +
        //      DPP row-reduce over l16; lane l16==0 stores 8 cols direct ----
        float o8[8] = {0.f, 0.f, 0.f, 0.f, 0.f, 0.f, 0.f, 0.f};
        #pragma unroll
        for (int it = 0; it < 4; ++it) {
            float wr = __shfl(wgt, it * 16 + l16);
            half8 hv = *((half8*)&Abuf[((it * 8 + w) * 64 + lane) * 8]);
            #pragma unroll
            for (int j = 0; j < 8; ++j)
                o8[j] = fmaf((float)hv[j], wr, o8[j]);
        }
        #pragma unroll
        for (int j = 0; j < 8; ++j)
            o8[j] = row16_sum(o8[j]);
        if (l16 == 0) {
            float* op = out + (size_t)bs * FF + w * 32 + quad * 8;
            float4 s0 = {o8[0], o8[1], o8[2], o8[3]};
            float4 s1 = {o8[4], o8[5], o8[6], o8[7]};
            *((float4*)op) = s0;
            *((float4*)(op + 4)) = s1;
        }
        // next iteration's stage writes the OTHER A buffer; BAR_A(i+1) orders
        // it against this slice's reads. SP rewrite is fenced by BAR_A(i+1).
    }
}

extern "C" void kernel_launch(void* const* d_in, const int* in_sizes, int n_in,
                              void* d_out, int out_size, void* d_ws, size_t ws_size,
                              hipStream_t stream) {
    const float* features = (const float*)d_in[0];
    const float* src_locs = (const float*)d_in[1];
    const float* tar_locs = (const float*)d_in[2];
    const float* W1       = (const float*)d_in[3];
    const float* b1       = (const float*)d_in[4];
    const float* W2       = (const float*)d_in[5];
    const float* b2       = (const float*)d_in[6];
    float* out = (float*)d_out;

    _Float16* whi = (_Float16*)d_ws;               // 128 KiB

    prep_w<<<dim3(FF * FF / 256), dim3(256), 0, stream>>>(W1, whi);
    ida_mfma<<<dim3(NBLK), dim3(512), 0, stream>>>(
        features, src_locs, tar_locs, whi, b1, W2, b2, out);
}